// Round 7
// baseline (16.986 us; speedup 1.0000x reference)
//
#include <hip/hip_runtime.h>
#include <math.h>

#define BATCH 8
#define NTR   1024   // tracks per batch
// output: [BATCH*NTR, 32], float32

// lexicographic (key,idx) compare: true if (bd,bi) < (ad,ai)
__device__ __forceinline__ bool lex_lt(float bd, int bi, float ad, int ai) {
    return (bd < ad) || ((bd == ad) && (bi < ai));
}

__device__ __forceinline__ void lex_min(float& dd, int& di,
                                        float ad, int ai, float bd, int bi) {
    const bool sw = lex_lt(bd, bi, ad, ai);
    dd = sw ? bd : ad;
    di = sw ? bi : ai;
}

// compare-exchange: after call (ad,ai) <= (bd,bi)
__device__ __forceinline__ void lex_ce(float& ad, int& ai, float& bd, int& bi) {
    const bool sw = lex_lt(bd, bi, ad, ai);
    const float tlo = sw ? bd : ad;
    const float thi = sw ? ad : bd;
    const int   ulo = sw ? bi : ai;
    const int   uhi = sw ? ai : bi;
    ad = tlo; bd = thi; ai = ulo; bi = uhi;
}

// branchless insert of (dd, j) into sorted-4 (strict <: lower j wins ties)
#define INSERT4(dd, j, D0, D1, D2, D3, I0, I1, I2, I3)              \
    {                                                               \
        const bool c3 = (dd) < D3;                                  \
        const bool c2 = (dd) < D2;                                  \
        const bool c1 = (dd) < D1;                                  \
        const bool c0 = (dd) < D0;                                  \
        D3 = c2 ? D2 : (c3 ? (dd) : D3);  I3 = c2 ? I2 : (c3 ? (j) : I3); \
        D2 = c1 ? D1 : (c2 ? (dd) : D2);  I2 = c1 ? I1 : (c2 ? (j) : I2); \
        D1 = c0 ? D0 : (c1 ? (dd) : D1);  I1 = c0 ? I0 : (c1 ? (j) : I1); \
        D0 = c0 ? (dd) : D0;              I0 = c0 ? (j) : I0;       \
    }

__global__ __launch_bounds__(256)
void knn_wave_row(const float* __restrict__ obs1,
                  const float* __restrict__ obs2,
                  const float* __restrict__ W,
                  const float* __restrict__ bias,
                  float* __restrict__ out)
{
    __shared__ __align__(16) float2 sh_pos[NTR];   // obs2[batch] only (8 KB)
    __shared__ float sh_d[256 * 4];                // 4 KB
    __shared__ int   sh_i[256 * 4];                // 4 KB

    const int tid   = threadIdx.x;
    const int lane  = tid & 63;
    const int wv    = tid >> 6;                    // wave in block: 0..3
    const int batch = blockIdx.x >> 8;             // 256 blocks per batch
    const int i     = ((blockIdx.x & 255) << 2) + wv;   // this wave's row

    // ---- stage obs2 into LDS (float4 = 2 tracks per op) ----
    const float4* __restrict__ p2 = (const float4*)(obs2 + (size_t)batch * NTR * 2);
    float4* sp4 = (float4*)sh_pos;
#pragma unroll
    for (int t = 0; t < 2; ++t) {
        const int idx = tid + (t << 8);
        sp4[idx] = p2[idx];
    }
    __syncthreads();

    const float2 my = sh_pos[i];   // wave-uniform broadcast read

    // ---- two independent 8-deep scan streams (2x ILP on insert chain) ----
    float aD0 = 3e38f, aD1 = 3e38f, aD2 = 3e38f, aD3 = 3e38f;
    int   aI0 = 0x7ffffffe, aI1 = 0x7ffffffe, aI2 = 0x7ffffffe, aI3 = 0x7ffffffe;
    float bD0 = 3e38f, bD1 = 3e38f, bD2 = 3e38f, bD3 = 3e38f;
    int   bI0 = 0x7ffffffe, bI1 = 0x7ffffffe, bI2 = 0x7ffffffe, bI3 = 0x7ffffffe;

#pragma unroll
    for (int c = 0; c < 8; ++c) {
        // stream A: j = lane + c*64
        {
            const int j = lane + (c << 6);
            const float2 pj = sh_pos[j];
            const float dx = pj.x - my.x;
            const float dy = pj.y - my.y;
            float dd = __fadd_rn(__fmul_rn(dx, dx), __fmul_rn(dy, dy));
            dd = (j == i) ? 3e38f : dd;           // mask diagonal
            INSERT4(dd, j, aD0, aD1, aD2, aD3, aI0, aI1, aI2, aI3);
        }
        // stream B: j = lane + (c+8)*64
        {
            const int j = lane + ((c + 8) << 6);
            const float2 pj = sh_pos[j];
            const float dx = pj.x - my.x;
            const float dy = pj.y - my.y;
            float dd = __fadd_rn(__fmul_rn(dx, dx), __fmul_rn(dy, dy));
            dd = (j == i) ? 3e38f : dd;
            INSERT4(dd, j, bD0, bD1, bD2, bD3, bI0, bI1, bI2, bI3);
        }
    }

    // ---- register bitonic merge of the two sorted-4 streams ----
    float t0, t1, t2, t3; int u0, u1, u2, u3;
    lex_min(t0, u0, aD0, aI0, bD3, bI3);
    lex_min(t1, u1, aD1, aI1, bD2, bI2);
    lex_min(t2, u2, aD2, aI2, bD1, bI1);
    lex_min(t3, u3, aD3, aI3, bD0, bI0);
    lex_ce(t0, u0, t2, u2);
    lex_ce(t1, u1, t3, u3);
    lex_ce(t0, u0, t1, u1);
    lex_ce(t2, u2, t3, u3);

    // ---- write per-thread sorted-4 to LDS ----
    {
        const int a = tid << 2;
        sh_d[a+0] = t0; sh_d[a+1] = t1; sh_d[a+2] = t2; sh_d[a+3] = t3;
        sh_i[a+0] = u0; sh_i[a+1] = u1; sh_i[a+2] = u2; sh_i[a+3] = u3;
    }

    // ---- 6-level LDS tree merge within each wave's 64 lanes ----
    for (int half = 32; half >= 1; half >>= 1) {
        __syncthreads();
        if (lane < half) {
            const int aa = tid << 2;
            const int bb = (tid + half) << 2;
            float a0 = sh_d[aa+0], a1 = sh_d[aa+1], a2 = sh_d[aa+2], a3 = sh_d[aa+3];
            int   x0 = sh_i[aa+0], x1 = sh_i[aa+1], x2 = sh_i[aa+2], x3 = sh_i[aa+3];
            float b0 = sh_d[bb+0], b1 = sh_d[bb+1], b2 = sh_d[bb+2], b3 = sh_d[bb+3];
            int   y0 = sh_i[bb+0], y1 = sh_i[bb+1], y2 = sh_i[bb+2], y3 = sh_i[bb+3];

            float m0, m1, m2, m3; int v0, v1, v2, v3;
            lex_min(m0, v0, a0, x0, b3, y3);
            lex_min(m1, v1, a1, x1, b2, y2);
            lex_min(m2, v2, a2, x2, b1, y1);
            lex_min(m3, v3, a3, x3, b0, y0);
            lex_ce(m0, v0, m2, v2);
            lex_ce(m1, v1, m3, v3);
            lex_ce(m0, v0, m1, v1);
            lex_ce(m2, v2, m3, v3);

            sh_d[aa+0] = m0; sh_d[aa+1] = m1; sh_d[aa+2] = m2; sh_d[aa+3] = m3;
            sh_i[aa+0] = v0; sh_i[aa+1] = v1; sh_i[aa+2] = v2; sh_i[aa+3] = v3;
        }
    }
    __syncthreads();

    // ---- epilogue: 4 rows x 32 outputs, one per thread (tid<128), coalesced ----
    if (tid < 128) {
        const int rr  = tid >> 5;               // row (= wave) 0..3
        const int kk  = (tid >> 3) & 3;         // neighbor rank
        const int e   = tid & 7;                // embedding dim
        const int row = ((blockIdx.x & 255) << 2) + rr;

        int j = sh_i[(rr << 8) + kk];           // thread (rr*64)'s result
        j = (j < 0) ? 0 : ((j > NTR - 1) ? NTR - 1 : j);   // defensive clamp

        const float2 pj  = sh_pos[j];
        const float2 myr = sh_pos[row];
        // velocities from global (L2-hot 128 KB dataset)
        const float2* __restrict__ o1 = (const float2*)(obs1 + (size_t)batch * NTR * 2);
        const float2 o1j = o1[j];
        const float2 o1r = o1[row];
        const float f0 = pj.x - myr.x;                      // rel_pos.x
        const float f1 = pj.y - myr.y;                      // rel_pos.y
        const float f2 = (pj.x - o1j.x) - (myr.x - o1r.x);  // rel_dir.x
        const float f3 = (pj.y - o1j.y) - (myr.y - o1r.y);  // rel_dir.y

        const float4 w = ((const float4*)W)[e];
        float r = f0 * w.x + f1 * w.y + f2 * w.z + f3 * w.w + bias[e];
        r = fmaxf(r, 0.0f);

        out[(((size_t)(batch * NTR + ((blockIdx.x & 255) << 2))) << 5) + tid] = r;
    }
}

extern "C" void kernel_launch(void* const* d_in, const int* in_sizes, int n_in,
                              void* d_out, int out_size, void* d_ws, size_t ws_size,
                              hipStream_t stream) {
    const float* obs1 = (const float*)d_in[0];
    const float* obs2 = (const float*)d_in[1];
    const float* W    = (const float*)d_in[2];
    const float* bias = (const float*)d_in[3];
    float* out = (float*)d_out;

    const int grid = BATCH * (NTR / 4);   // 2048 blocks = 8/CU, 32 waves/CU
    knn_wave_row<<<grid, 256, 0, stream>>>(obs1, obs2, W, bias, out);
}

// Round 8
// 11.984 us; speedup vs baseline: 1.4175x; 1.4175x over previous
//
#include <hip/hip_runtime.h>
#include <math.h>

#define BATCH 8
#define NTR   1024   // tracks per batch
// output: [BATCH*NTR, 32], float32

__global__ __launch_bounds__(256)
void knn_mm3(const float* __restrict__ obs1,
             const float* __restrict__ obs2,
             const float* __restrict__ W,
             const float* __restrict__ bias,
             float* __restrict__ out)
{
    __shared__ __align__(16) float2 sh_pos[NTR];   // obs2[batch] (8 KB)
    __shared__ __align__(16) float4 sh_v[256];     // per-lane sorted-4 values (4 KB)
    __shared__ int sh_idx[4][4];                   // per-wave top-4 indices

    const int tid   = threadIdx.x;
    const int lane  = tid & 63;
    const int wv    = tid >> 6;                    // wave in block: 0..3
    const int batch = blockIdx.x >> 8;             // 256 blocks per batch
    const int i     = ((blockIdx.x & 255) << 2) + wv;   // this wave's row

    // ---- stage obs2 into LDS (float4 = 2 tracks per op) ----
    const float4* __restrict__ p2 = (const float4*)(obs2 + (size_t)batch * NTR * 2);
    float4* sp4 = (float4*)sh_pos;
    sp4[tid]       = p2[tid];
    sp4[tid + 256] = p2[tid + 256];
    __syncthreads();

    const float2 my = sh_pos[i];   // wave-uniform broadcast read

    // ---- pass 1: values-only sorted top-4 via min/med3 (4 ops/insert) ----
    float s0 = 3e38f, s1 = 3e38f, s2 = 3e38f, s3 = 3e38f;
    float dd[16];                  // cached squared distances (registers)

#pragma unroll
    for (int c = 0; c < 16; ++c) {
        const int j = lane + (c << 6);
        const float2 pj = sh_pos[j];
        const float dx = pj.x - my.x;
        const float dy = pj.y - my.y;
        // unfused x*x + y*y (monotone equivalent of the reference's norm)
        float d = __fadd_rn(__fmul_rn(dx, dx), __fmul_rn(dy, dy));
        d = (j == i) ? 3e38f : d;              // mask diagonal
        dd[c] = d;
        // insert d into sorted (s0<=s1<=s2<=s3), drop largest: depth-1 network
        const float t0 = fminf(s0, d);
        const float t1 = __builtin_amdgcn_fmed3f(s0, s1, d);
        const float t2 = __builtin_amdgcn_fmed3f(s1, s2, d);
        const float t3 = __builtin_amdgcn_fmed3f(s2, s3, d);
        s0 = t0; s1 = t1; s2 = t2; s3 = t3;
    }

    // ---- values-only LDS tree merge: 64 sorted-4 lists -> 1 per wave ----
    sh_v[tid] = make_float4(s0, s1, s2, s3);
    for (int half = 32; half >= 1; half >>= 1) {
        __syncthreads();
        if (lane < half) {
            const float4 o = sh_v[tid + half];
            // bitonic lower-half: mine ascending vs other's reversed
            float m0 = fminf(s0, o.w);
            float m1 = fminf(s1, o.z);
            float m2 = fminf(s2, o.y);
            float m3 = fminf(s3, o.x);
            // sort the bitonic 4: CE(0,2) CE(1,3) CE(0,1) CE(2,3)
            float a, b;
            a = fminf(m0, m2); b = fmaxf(m0, m2); m0 = a; m2 = b;
            a = fminf(m1, m3); b = fmaxf(m1, m3); m1 = a; m3 = b;
            a = fminf(m0, m1); b = fmaxf(m0, m1); m0 = a; m1 = b;
            a = fminf(m2, m3); b = fmaxf(m2, m3); m2 = a; m3 = b;
            s0 = m0; s1 = m1; s2 = m2; s3 = m3;
            sh_v[tid] = make_float4(s0, s1, s2, s3);
        }
    }
    __syncthreads();

    // row's global sorted top-4 distances (wave-uniform broadcast)
    const float4 v = sh_v[wv << 6];

    // ---- pass 2: recover indices from cached dds (exactly 4 hits/row) ----
#pragma unroll
    for (int c = 0; c < 16; ++c) {
        if (dd[c] <= v.w) {                     // rare: ~4 of 1024 per row
            const int j = lane + (c << 6);
            const int rank = (int)(dd[c] > v.x) + (int)(dd[c] > v.y)
                           + (int)(dd[c] > v.z);
            sh_idx[wv][rank] = j;
        }
    }
    __syncthreads();

    // ---- epilogue: 4 rows x 32 outputs, one per thread (tid<128), coalesced ----
    if (tid < 128) {
        const int rr  = tid >> 5;               // row (= wave) 0..3
        const int kk  = (tid >> 3) & 3;         // neighbor rank
        const int e   = tid & 7;                // embedding dim
        const int row = ((blockIdx.x & 255) << 2) + rr;

        int j = sh_idx[rr][kk] & (NTR - 1);     // defensive in-bounds

        const float2 pj  = sh_pos[j];
        const float2 myr = sh_pos[row];
        const float2* __restrict__ o1 = (const float2*)(obs1 + (size_t)batch * NTR * 2);
        const float2 o1j = o1[j];
        const float2 o1r = o1[row];
        const float f0 = pj.x - myr.x;                      // rel_pos.x
        const float f1 = pj.y - myr.y;                      // rel_pos.y
        const float f2 = (pj.x - o1j.x) - (myr.x - o1r.x);  // rel_dir.x
        const float f3 = (pj.y - o1j.y) - (myr.y - o1r.y);  // rel_dir.y

        const float4 w = ((const float4*)W)[e];
        float r = f0 * w.x + f1 * w.y + f2 * w.z + f3 * w.w + bias[e];
        r = fmaxf(r, 0.0f);

        out[(((size_t)(batch * NTR + ((blockIdx.x & 255) << 2))) << 5) + tid] = r;
    }
}

extern "C" void kernel_launch(void* const* d_in, const int* in_sizes, int n_in,
                              void* d_out, int out_size, void* d_ws, size_t ws_size,
                              hipStream_t stream) {
    const float* obs1 = (const float*)d_in[0];
    const float* obs2 = (const float*)d_in[1];
    const float* W    = (const float*)d_in[2];
    const float* bias = (const float*)d_in[3];
    float* out = (float*)d_out;

    const int grid = BATCH * (NTR / 4);   // 2048 blocks, wave per row, 8/CU
    knn_mm3<<<grid, 256, 0, stream>>>(obs1, obs2, W, bias, out);
}

// Round 9
// 11.790 us; speedup vs baseline: 1.4408x; 1.0164x over previous
//
#include <hip/hip_runtime.h>
#include <math.h>

#define BATCH 8
#define NTR   1024   // tracks per batch
// output: [BATCH*NTR, 32], float32

__global__ __launch_bounds__(256)
void knn_v9(const float* __restrict__ obs1,
            const float* __restrict__ obs2,
            const float* __restrict__ W,
            const float* __restrict__ bias,
            float* __restrict__ out)
{
    __shared__ __align__(16) float2 sh_pos[NTR];   // obs2[batch] (8 KB)
    __shared__ __align__(16) float4 sh_v[256];     // per-lane sorted-4 values (4 KB)
    __shared__ int sh_idx[4][4];                   // per-wave top-4 indices

    const int tid   = threadIdx.x;
    const int lane  = tid & 63;
    const int wv    = tid >> 6;                    // wave in block: 0..3
    const int batch = blockIdx.x >> 8;             // 256 blocks per batch
    const int i     = ((blockIdx.x & 255) << 2) + wv;   // this wave's row

    // ---- stage obs2 into LDS (float4 = 2 tracks per op) ----
    const float4* __restrict__ p2 = (const float4*)(obs2 + (size_t)batch * NTR * 2);
    float4* sp4 = (float4*)sh_pos;
    sp4[tid]       = p2[tid];
    sp4[tid + 256] = p2[tid + 256];
    __syncthreads();                               // barrier #1 (cross-wave staging)

    const float2 my = sh_pos[i];   // wave-uniform broadcast read

    // self-candidate bookkeeping: wave-uniform iteration c_self, per-lane flags
    const int  c_self    = i >> 7;                         // 0..7
    const bool self_even = (lane == ((i >> 1) & 63)) && ((i & 1) == 0);
    const bool self_odd  = (lane == ((i >> 1) & 63)) && ((i & 1) == 1);

    // ---- pass 1: 2 candidates per ds_read_b128, min/med3 sorted-4 ----
    float s0 = 3e38f, s1 = 3e38f, s2 = 3e38f, s3 = 3e38f;
    float dd[16];                  // cached squared distances (unrolled -> VGPRs)

    const float4* pos4 = (const float4*)sh_pos;
#pragma unroll
    for (int c = 0; c < 8; ++c) {
        const float4 pq = pos4[(c << 6) + lane];   // tracks 2*(c*64+lane), +1
        const float dx0 = pq.x - my.x;
        const float dy0 = pq.y - my.y;
        const float dx1 = pq.z - my.x;
        const float dy1 = pq.w - my.y;
        // unfused x*x + y*y (bit-exact vs reference's norm argument)
        float d0 = __fadd_rn(__fmul_rn(dx0, dx0), __fmul_rn(dy0, dy0));
        float d1 = __fadd_rn(__fmul_rn(dx1, dx1), __fmul_rn(dy1, dy1));
        if (c == c_self) {                         // wave-uniform scalar branch
            d0 = self_even ? 3e38f : d0;
            d1 = self_odd  ? 3e38f : d1;
        }
        dd[2 * c]     = d0;
        dd[2 * c + 1] = d1;
        // insert d0 into sorted (s0<=s1<=s2<=s3), drop largest
        {
            const float t0 = fminf(s0, d0);
            const float t1 = __builtin_amdgcn_fmed3f(s0, s1, d0);
            const float t2 = __builtin_amdgcn_fmed3f(s1, s2, d0);
            const float t3 = __builtin_amdgcn_fmed3f(s2, s3, d0);
            s0 = t0; s1 = t1; s2 = t2; s3 = t3;
        }
        // insert d1
        {
            const float t0 = fminf(s0, d1);
            const float t1 = __builtin_amdgcn_fmed3f(s0, s1, d1);
            const float t2 = __builtin_amdgcn_fmed3f(s1, s2, d1);
            const float t3 = __builtin_amdgcn_fmed3f(s2, s3, d1);
            s0 = t0; s1 = t1; s2 = t2; s3 = t3;
        }
    }

    // ---- intra-wave values-only LDS tree merge (NO block barriers:
    //      each wave touches only its own 64-entry sh_v slice; DS ops of a
    //      wave complete in issue order, so a compiler fence suffices) ----
    sh_v[tid] = make_float4(s0, s1, s2, s3);
    asm volatile("" ::: "memory");
#pragma unroll
    for (int half = 32; half >= 1; half >>= 1) {
        if (lane < half) {
            const float4 o = sh_v[tid + half];
            // bitonic lower-half: mine ascending vs other's reversed
            float m0 = fminf(s0, o.w);
            float m1 = fminf(s1, o.z);
            float m2 = fminf(s2, o.y);
            float m3 = fminf(s3, o.x);
            // sort the bitonic 4: CE(0,2) CE(1,3) CE(0,1) CE(2,3)
            float a;
            a = fminf(m0, m2); m2 = fmaxf(m0, m2); m0 = a;
            a = fminf(m1, m3); m3 = fmaxf(m1, m3); m1 = a;
            a = fminf(m0, m1); m1 = fmaxf(m0, m1); m0 = a;
            a = fminf(m2, m3); m3 = fmaxf(m2, m3); m2 = a;
            s0 = m0; s1 = m1; s2 = m2; s3 = m3;
            sh_v[tid] = make_float4(s0, s1, s2, s3);
        }
        asm volatile("" ::: "memory");
    }

    // row's global sorted top-4 distances (intra-wave broadcast)
    const float4 v = sh_v[wv << 6];

    // ---- pass 2: recover indices from cached dds (exactly 4 hits/row) ----
#pragma unroll
    for (int k = 0; k < 16; ++k) {
        if (dd[k] <= v.w) {                        // rare: ~4 of 1024 per row
            const int j = ((k >> 1) << 7) + (lane << 1) + (k & 1);
            const int rank = (int)(dd[k] > v.x) + (int)(dd[k] > v.y)
                           + (int)(dd[k] > v.z);
            sh_idx[wv][rank] = j;
        }
    }
    __syncthreads();                               // barrier #2 (cross-wave epilogue)

    // ---- epilogue: 4 rows x 32 outputs, one per thread (tid<128), coalesced ----
    if (tid < 128) {
        const int rr  = tid >> 5;                  // row (= wave) 0..3
        const int kk  = (tid >> 3) & 3;            // neighbor rank
        const int e   = tid & 7;                   // embedding dim
        const int row = ((blockIdx.x & 255) << 2) + rr;

        int j = sh_idx[rr][kk] & (NTR - 1);        // defensive in-bounds

        const float2 pj  = sh_pos[j];
        const float2 myr = sh_pos[row];
        const float2* __restrict__ o1 = (const float2*)(obs1 + (size_t)batch * NTR * 2);
        const float2 o1j = o1[j];
        const float2 o1r = o1[row];
        const float f0 = pj.x - myr.x;                      // rel_pos.x
        const float f1 = pj.y - myr.y;                      // rel_pos.y
        const float f2 = (pj.x - o1j.x) - (myr.x - o1r.x);  // rel_dir.x
        const float f3 = (pj.y - o1j.y) - (myr.y - o1r.y);  // rel_dir.y

        const float4 w = ((const float4*)W)[e];
        float r = f0 * w.x + f1 * w.y + f2 * w.z + f3 * w.w + bias[e];
        r = fmaxf(r, 0.0f);

        out[(((size_t)(batch * NTR + ((blockIdx.x & 255) << 2))) << 5) + tid] = r;
    }
}

extern "C" void kernel_launch(void* const* d_in, const int* in_sizes, int n_in,
                              void* d_out, int out_size, void* d_ws, size_t ws_size,
                              hipStream_t stream) {
    const float* obs1 = (const float*)d_in[0];
    const float* obs2 = (const float*)d_in[1];
    const float* W    = (const float*)d_in[2];
    const float* bias = (const float*)d_in[3];
    float* out = (float*)d_out;

    const int grid = BATCH * (NTR / 4);   // 2048 blocks, wave per row, 8/CU
    knn_v9<<<grid, 256, 0, stream>>>(obs1, obs2, W, bias, out);
}

// Round 10
// 11.384 us; speedup vs baseline: 1.4922x; 1.0357x over previous
//
#include <hip/hip_runtime.h>
#include <math.h>

#define BATCH 8
#define NTR   1024   // tracks per batch
// output: [BATCH*NTR, 32], float32

__global__ __launch_bounds__(256)
void knn_v10(const float* __restrict__ obs1,
             const float* __restrict__ obs2,
             const float* __restrict__ W,
             const float* __restrict__ bias,
             float* __restrict__ out)
{
    __shared__ __align__(16) float2 sh_pos[NTR];   // obs2[batch] (8 KB)
    __shared__ __align__(16) float4 sh_v[256];     // per-lane sorted-4 values (4 KB)
    __shared__ int sh_idx[4][4];                   // per-wave top-4 indices (wave-private)

    const int tid   = threadIdx.x;
    const int lane  = tid & 63;
    const int wv    = tid >> 6;                    // wave in block: 0..3
    const int batch = blockIdx.x >> 8;             // 256 blocks per batch
    const int i     = ((blockIdx.x & 255) << 2) + wv;   // this wave's row

    // ---- stage obs2 into LDS (float4 = 2 tracks per op) ----
    const float4* __restrict__ p2 = (const float4*)(obs2 + (size_t)batch * NTR * 2);
    float4* sp4 = (float4*)sh_pos;
    sp4[tid]       = p2[tid];
    sp4[tid + 256] = p2[tid + 256];
    __syncthreads();                               // the ONLY barrier

    const float2 my = sh_pos[i];   // wave-uniform broadcast read

    // self-candidate bookkeeping (wave-uniform iteration, per-lane flags)
    const int  c_self    = i >> 7;                         // 0..7
    const bool self_even = (lane == ((i >> 1) & 63)) && ((i & 1) == 0);
    const bool self_odd  = (lane == ((i >> 1) & 63)) && ((i & 1) == 1);

    // ---- pass 1: 2 candidates per ds_read_b128, min/med3 sorted-4 ----
    float s0 = 3e38f, s1 = 3e38f, s2 = 3e38f, s3 = 3e38f;
    float dd[16];                  // cached squared distances (unrolled -> VGPRs)

    const float4* pos4 = (const float4*)sh_pos;
#pragma unroll
    for (int c = 0; c < 8; ++c) {
        const float4 pq = pos4[(c << 6) + lane];   // tracks 2*(c*64+lane), +1
        const float dx0 = pq.x - my.x;
        const float dy0 = pq.y - my.y;
        const float dx1 = pq.z - my.x;
        const float dy1 = pq.w - my.y;
        // mul + fma (order-equivalent to reference's sum-of-squares)
        float d0 = __fmaf_rn(dy0, dy0, __fmul_rn(dx0, dx0));
        float d1 = __fmaf_rn(dy1, dy1, __fmul_rn(dx1, dx1));
        if (c == c_self) {                         // wave-uniform scalar branch
            d0 = self_even ? 3e38f : d0;
            d1 = self_odd  ? 3e38f : d1;
        }
        dd[2 * c]     = d0;
        dd[2 * c + 1] = d1;
        // insert d0 into sorted (s0<=s1<=s2<=s3), drop largest: depth-1 network
        {
            const float t0 = fminf(s0, d0);
            const float t1 = __builtin_amdgcn_fmed3f(s0, s1, d0);
            const float t2 = __builtin_amdgcn_fmed3f(s1, s2, d0);
            const float t3 = __builtin_amdgcn_fmed3f(s2, s3, d0);
            s0 = t0; s1 = t1; s2 = t2; s3 = t3;
        }
        // insert d1
        {
            const float t0 = fminf(s0, d1);
            const float t1 = __builtin_amdgcn_fmed3f(s0, s1, d1);
            const float t2 = __builtin_amdgcn_fmed3f(s1, s2, d1);
            const float t3 = __builtin_amdgcn_fmed3f(s2, s3, d1);
            s0 = t0; s1 = t1; s2 = t2; s3 = t3;
        }
    }

    // ---- intra-wave values-only LDS tree merge (no block barriers:
    //      each wave owns a disjoint 64-entry sh_v slice; a wave's DS ops
    //      complete in issue order, compiler fence prevents reordering) ----
    sh_v[tid] = make_float4(s0, s1, s2, s3);
    asm volatile("" ::: "memory");
#pragma unroll
    for (int half = 32; half >= 1; half >>= 1) {
        if (lane < half) {
            const float4 o = sh_v[tid + half];
            float m0 = fminf(s0, o.w);
            float m1 = fminf(s1, o.z);
            float m2 = fminf(s2, o.y);
            float m3 = fminf(s3, o.x);
            float a;
            a = fminf(m0, m2); m2 = fmaxf(m0, m2); m0 = a;
            a = fminf(m1, m3); m3 = fmaxf(m1, m3); m1 = a;
            a = fminf(m0, m1); m1 = fmaxf(m0, m1); m0 = a;
            a = fminf(m2, m3); m3 = fmaxf(m2, m3); m2 = a;
            s0 = m0; s1 = m1; s2 = m2; s3 = m3;
            sh_v[tid] = make_float4(s0, s1, s2, s3);
        }
        asm volatile("" ::: "memory");
    }

    // row's global sorted top-4 distances (intra-wave broadcast)
    const float4 v = sh_v[wv << 6];

    // ---- pass 2: recover indices from cached dds (exactly 4 hits/row) ----
#pragma unroll
    for (int k = 0; k < 16; ++k) {
        if (dd[k] <= v.w) {                        // rare: ~4 of 1024 per row
            const int j = ((k >> 1) << 7) + (lane << 1) + (k & 1);
            const int rank = (int)(dd[k] > v.x) + (int)(dd[k] > v.y)
                           + (int)(dd[k] > v.z);
            sh_idx[wv][rank] = j;
        }
    }
    asm volatile("" ::: "memory");                 // wave-private sh_idx: no barrier

    // ---- per-wave epilogue: lanes 0..31 write this wave's row (128 B) ----
    if (lane < 32) {
        const int kk = lane >> 3;                  // neighbor rank 0..3
        const int e  = lane & 7;                   // embedding dim 0..7

        int j = sh_idx[wv][kk] & (NTR - 1);        // defensive in-bounds

        const float2 pj  = sh_pos[j];
        const float2* __restrict__ o1 = (const float2*)(obs1 + (size_t)batch * NTR * 2);
        const float2 o1j = o1[j];
        const float2 o1r = o1[i];
        const float f0 = pj.x - my.x;                       // rel_pos.x
        const float f1 = pj.y - my.y;                       // rel_pos.y
        const float f2 = (pj.x - o1j.x) - (my.x - o1r.x);   // rel_dir.x
        const float f3 = (pj.y - o1j.y) - (my.y - o1r.y);   // rel_dir.y

        const float4 w = ((const float4*)W)[e];
        float r = f0 * w.x + f1 * w.y + f2 * w.z + f3 * w.w + bias[e];
        r = fmaxf(r, 0.0f);

        out[(((size_t)(batch * NTR + i)) << 5) + lane] = r;
    }
}

extern "C" void kernel_launch(void* const* d_in, const int* in_sizes, int n_in,
                              void* d_out, int out_size, void* d_ws, size_t ws_size,
                              hipStream_t stream) {
    const float* obs1 = (const float*)d_in[0];
    const float* obs2 = (const float*)d_in[1];
    const float* W    = (const float*)d_in[2];
    const float* bias = (const float*)d_in[3];
    float* out = (float*)d_out;

    const int grid = BATCH * (NTR / 4);   // 2048 blocks, wave per row, 8/CU
    knn_v10<<<grid, 256, 0, stream>>>(obs1, obs2, W, bias, out);
}

// Round 11
// 10.855 us; speedup vs baseline: 1.5649x; 1.0487x over previous
//
#include <hip/hip_runtime.h>
#include <math.h>

#define BATCH 8
#define NTR   1024   // tracks per batch
// output: [BATCH*NTR, 32], float32

// DPP-based partner fetch (compile-time ctrl); works within 16-lane rows
template<int CTRL>
__device__ __forceinline__ float dpp_f(float x) {
    union { float f; int i; } u;
    u.f = x;
    u.i = __builtin_amdgcn_mov_dpp(u.i, CTRL, 0xF, 0xF, false);
    return u.f;
}

// ds_swizzle xor16 (BitMode: xor=16, and=0x1F) — lane^16 within each 32-half,
// which equals lane^16 across wave64 (bit4 flip never crosses the halves)
__device__ __forceinline__ float swz16(float x) {
    union { float f; int i; } u;
    u.f = x;
    u.i = __builtin_amdgcn_ds_swizzle(u.i, 0x401F);
    return u.f;
}

// merge my ascending (s0..s3) with partner's ascending (e0..e3): keep 4 smallest
#define MERGE4(E0, E1, E2, E3)                              \
    {                                                       \
        float m0 = fminf(s0, (E3));                         \
        float m1 = fminf(s1, (E2));                         \
        float m2 = fminf(s2, (E1));                         \
        float m3 = fminf(s3, (E0));                         \
        float a;                                            \
        a = fminf(m0, m2); m2 = fmaxf(m0, m2); m0 = a;      \
        a = fminf(m1, m3); m3 = fmaxf(m1, m3); m1 = a;      \
        a = fminf(m0, m1); m1 = fmaxf(m0, m1); m0 = a;      \
        a = fminf(m2, m3); m3 = fmaxf(m2, m3); m2 = a;      \
        s0 = m0; s1 = m1; s2 = m2; s3 = m3;                 \
    }

__global__ __launch_bounds__(256)
void knn_v11(const float* __restrict__ obs1,
             const float* __restrict__ obs2,
             const float* __restrict__ W,
             const float* __restrict__ bias,
             float* __restrict__ out)
{
    __shared__ __align__(16) float2 sh_pos[NTR];   // obs2[batch] (8 KB)
    __shared__ __align__(16) float4 sh_x[256];     // level-32 exchange (4 KB)
    __shared__ int sh_idx[4][4];                   // per-wave top-4 indices

    const int tid   = threadIdx.x;
    const int lane  = tid & 63;
    const int wv    = tid >> 6;                    // wave in block: 0..3
    const int batch = blockIdx.x >> 8;             // 256 blocks per batch
    const int i     = ((blockIdx.x & 255) << 2) + wv;   // this wave's row

    // ---- stage obs2 into LDS (float4 = 2 tracks per op) ----
    const float4* __restrict__ p2 = (const float4*)(obs2 + (size_t)batch * NTR * 2);
    float4* sp4 = (float4*)sh_pos;
    sp4[tid]       = p2[tid];
    sp4[tid + 256] = p2[tid + 256];
    __syncthreads();                               // the ONLY barrier

    const float2 my = sh_pos[i];   // wave-uniform broadcast read

    // self-candidate bookkeeping (wave-uniform iteration, per-lane flags)
    const int  c_self    = i >> 7;                         // 0..7
    const bool self_even = (lane == ((i >> 1) & 63)) && ((i & 1) == 0);
    const bool self_odd  = (lane == ((i >> 1) & 63)) && ((i & 1) == 1);

    // ---- pass 1: 2 candidates per ds_read_b128, min/med3 sorted-4 ----
    float s0 = 3e38f, s1 = 3e38f, s2 = 3e38f, s3 = 3e38f;
    float dd[16];                  // cached squared distances (unrolled -> VGPRs)

    const float4* pos4 = (const float4*)sh_pos;
#pragma unroll
    for (int c = 0; c < 8; ++c) {
        const float4 pq = pos4[(c << 6) + lane];   // tracks 2*(c*64+lane), +1
        const float dx0 = pq.x - my.x;
        const float dy0 = pq.y - my.y;
        const float dx1 = pq.z - my.x;
        const float dy1 = pq.w - my.y;
        float d0 = __fmaf_rn(dy0, dy0, __fmul_rn(dx0, dx0));
        float d1 = __fmaf_rn(dy1, dy1, __fmul_rn(dx1, dx1));
        if (c == c_self) {                         // wave-uniform scalar branch
            d0 = self_even ? 3e38f : d0;
            d1 = self_odd  ? 3e38f : d1;
        }
        dd[2 * c]     = d0;
        dd[2 * c + 1] = d1;
        {   // insert d0 into sorted (s0<=s1<=s2<=s3): depth-1 min/med3 network
            const float t0 = fminf(s0, d0);
            const float t1 = __builtin_amdgcn_fmed3f(s0, s1, d0);
            const float t2 = __builtin_amdgcn_fmed3f(s1, s2, d0);
            const float t3 = __builtin_amdgcn_fmed3f(s2, s3, d0);
            s0 = t0; s1 = t1; s2 = t2; s3 = t3;
        }
        {   // insert d1
            const float t0 = fminf(s0, d1);
            const float t1 = __builtin_amdgcn_fmed3f(s0, s1, d1);
            const float t2 = __builtin_amdgcn_fmed3f(s1, s2, d1);
            const float t3 = __builtin_amdgcn_fmed3f(s2, s3, d1);
            s0 = t0; s1 = t1; s2 = t2; s3 = t3;
        }
    }

    // ---- values-only wave merge, VALU-side (DPP + swizzle + 1 LDS level) ----
    // L1: xor1 = quad_perm [1,0,3,2] (0xB1)
    MERGE4(dpp_f<0xB1>(s0), dpp_f<0xB1>(s1), dpp_f<0xB1>(s2), dpp_f<0xB1>(s3));
    // L2: xor2 = quad_perm [2,3,0,1] (0x4E)
    MERGE4(dpp_f<0x4E>(s0), dpp_f<0x4E>(s1), dpp_f<0x4E>(s2), dpp_f<0x4E>(s3));
    // L4: row_half_mirror (0x141) — pairs lower/upper 4 within each 8
    MERGE4(dpp_f<0x141>(s0), dpp_f<0x141>(s1), dpp_f<0x141>(s2), dpp_f<0x141>(s3));
    // L8: row_mirror (0x140) — pairs lower/upper 8 within each 16
    MERGE4(dpp_f<0x140>(s0), dpp_f<0x140>(s1), dpp_f<0x140>(s2), dpp_f<0x140>(s3));
    // L16: ds_swizzle xor16
    MERGE4(swz16(s0), swz16(s1), swz16(s2), swz16(s3));
    // L32: one LDS float4 exchange with lane^32 (intra-wave, fence only)
    sh_x[tid] = make_float4(s0, s1, s2, s3);
    asm volatile("" ::: "memory");
    {
        const float4 o = sh_x[tid ^ 32];
        MERGE4(o.x, o.y, o.z, o.w);
    }
    // now every lane holds the row's global sorted top-4 in s0..s3

    // ---- pass 2: recover indices from cached dds (exactly 4 hits/row) ----
#pragma unroll
    for (int k = 0; k < 16; ++k) {
        if (dd[k] <= s3) {                        // rare: ~4 of 1024 per row
            const int j = ((k >> 1) << 7) + (lane << 1) + (k & 1);
            const int rank = (int)(dd[k] > s0) + (int)(dd[k] > s1)
                           + (int)(dd[k] > s2);
            sh_idx[wv][rank] = j;
        }
    }
    asm volatile("" ::: "memory");                 // wave-private sh_idx

    // ---- per-wave epilogue: lanes 0..31 write this wave's row (128 B) ----
    if (lane < 32) {
        const int kk = lane >> 3;                  // neighbor rank 0..3
        const int e  = lane & 7;                   // embedding dim 0..7

        int j = sh_idx[wv][kk] & (NTR - 1);        // defensive in-bounds

        const float2 pj  = sh_pos[j];
        const float2* __restrict__ o1 = (const float2*)(obs1 + (size_t)batch * NTR * 2);
        const float2 o1j = o1[j];
        const float2 o1r = o1[i];
        const float f0 = pj.x - my.x;                       // rel_pos.x
        const float f1 = pj.y - my.y;                       // rel_pos.y
        const float f2 = (pj.x - o1j.x) - (my.x - o1r.x);   // rel_dir.x
        const float f3 = (pj.y - o1j.y) - (my.y - o1r.y);   // rel_dir.y

        const float4 w = ((const float4*)W)[e];
        float r = f0 * w.x + f1 * w.y + f2 * w.z + f3 * w.w + bias[e];
        r = fmaxf(r, 0.0f);

        out[(((size_t)(batch * NTR + i)) << 5) + lane] = r;
    }
}

extern "C" void kernel_launch(void* const* d_in, const int* in_sizes, int n_in,
                              void* d_out, int out_size, void* d_ws, size_t ws_size,
                              hipStream_t stream) {
    const float* obs1 = (const float*)d_in[0];
    const float* obs2 = (const float*)d_in[1];
    const float* W    = (const float*)d_in[2];
    const float* bias = (const float*)d_in[3];
    float* out = (float*)d_out;

    const int grid = BATCH * (NTR / 4);   // 2048 blocks, wave per row, 8/CU
    knn_v11<<<grid, 256, 0, stream>>>(obs1, obs2, W, bias, out);
}